// Round 1
// baseline (857.040 us; speedup 1.0000x reference)
//
#include <hip/hip_runtime.h>

// CenterLoss: features [B,D] f32, centers [C,D] f32, labels [B] int
// out = [loss (1 f32)] ++ [new_centers (C*D f32)]
// new_centers[c] = count[c]>0 ? 0.5*centers[c] + 0.5*mean_c : centers[c]

constexpr int B = 16384;
constexpr int D = 128;
constexpr int C = 1000000;
constexpr int QPR = D / 4;      // float4 quads per row = 32
constexpr float ALPHA = 0.5f;   // momentum
// LAMBDA_C = 1.0 folded in

__global__ void count_k(const int* __restrict__ labels, int* __restrict__ counts) {
    int b = blockIdx.x * 256 + threadIdx.x;
    if (b < B) atomicAdd(counts + labels[b], 1);
}

__global__ void loss_k(const float4* __restrict__ f4,
                       const float4* __restrict__ c4,
                       const int* __restrict__ labels,
                       float* __restrict__ out) {
    int tid = blockIdx.x * blockDim.x + threadIdx.x;
    int nth = gridDim.x * blockDim.x;
    float acc = 0.f;
    for (int idx = tid; idx < B * QPR; idx += nth) {
        int b = idx >> 5;          // idx / QPR
        int q = idx & (QPR - 1);
        float4 f = f4[idx];
        float4 c = c4[(long long)labels[b] * QPR + q];
        float dx = f.x - c.x, dy = f.y - c.y, dz = f.z - c.z, dw = f.w - c.w;
        acc += dx * dx + dy * dy + dz * dz + dw * dw;
    }
    // wave-64 reduce
    for (int off = 32; off > 0; off >>= 1)
        acc += __shfl_down(acc, off, 64);
    __shared__ float ws[4];
    int lane = threadIdx.x & 63, wid = threadIdx.x >> 6;
    if (lane == 0) ws[wid] = acc;
    __syncthreads();
    if (threadIdx.x == 0) {
        float s = ws[0] + ws[1] + ws[2] + ws[3];
        atomicAdd(out, s * (1.0f / (2.0f * (float)B)));
    }
}

// The BW-bound kernel: copy centers -> out, pre-scaled by 0.5 for present rows.
__global__ void copy_k(const float4* __restrict__ c4,
                       const int* __restrict__ counts,
                       float* __restrict__ outc) {
    int idx = blockIdx.x * 256 + threadIdx.x;   // quad index, < 32e6 fits int
    if (idx >= C * QPR) return;
    int row = idx >> 5;                         // idx / QPR
    float scale = (counts[row] > 0) ? ALPHA : 1.0f;
    float4 v = c4[idx];
    float* p = outc + idx * 4;                  // outc is d_out+1: 16B-misaligned, scalar stores
    p[0] = v.x * scale;
    p[1] = v.y * scale;
    p[2] = v.z * scale;
    p[3] = v.w * scale;
}

// Accumulate 0.5 * features[b] / count into present rows.
__global__ void scatter_k(const float4* __restrict__ f4,
                          const int* __restrict__ labels,
                          const int* __restrict__ counts,
                          float* __restrict__ outc) {
    int idx = blockIdx.x * 256 + threadIdx.x;
    if (idx >= B * QPR) return;
    int b = idx >> 5, q = idx & (QPR - 1);
    int lbl = labels[b];
    float inv = ALPHA / (float)counts[lbl];
    float4 f = f4[idx];
    float* p = outc + lbl * D + q * 4;
    atomicAdd(p + 0, f.x * inv);
    atomicAdd(p + 1, f.y * inv);
    atomicAdd(p + 2, f.z * inv);
    atomicAdd(p + 3, f.w * inv);
}

extern "C" void kernel_launch(void* const* d_in, const int* in_sizes, int n_in,
                              void* d_out, int out_size, void* d_ws, size_t ws_size,
                              hipStream_t stream) {
    const float* features = (const float*)d_in[0];
    const float* centers  = (const float*)d_in[1];
    const int*   labels   = (const int*)d_in[2];
    float* out = (float*)d_out;
    int* counts = (int*)d_ws;   // C ints = 4 MB

    hipMemsetAsync(counts, 0, (size_t)C * sizeof(int), stream);
    hipMemsetAsync(d_out, 0, sizeof(float), stream);   // loss accumulator

    count_k<<<(B + 255) / 256, 256, 0, stream>>>(labels, counts);
    loss_k<<<1024, 256, 0, stream>>>((const float4*)features, (const float4*)centers,
                                     labels, out);
    copy_k<<<(C * QPR + 255) / 256, 256, 0, stream>>>((const float4*)centers, counts,
                                                      out + 1);
    scatter_k<<<(B * QPR + 255) / 256, 256, 0, stream>>>((const float4*)features, labels,
                                                         counts, out + 1);
}